// Round 4
// baseline (102.290 us; speedup 1.0000x reference)
//
#include <hip/hip_runtime.h>

// EMA1D straight-through: forward value is exactly x, so this is a pure
// 256 MiB -> 256 MiB streaming copy. HBM-bound.
// R1 (1 load in flight/wave): 112 us = 4.79 TB/s.
// R2 (4 loads, 8 MiB apart + nt): 126 us — power-of-2 channel aliasing.
// R3 (4 loads, 4 KiB apart, contiguous 16 KiB chunks): 98.9 us = 5.43 TB/s.
// R4: 8 loads in flight per wave (32 KiB chunks) — deeper MLP, same
//     contiguous non-aliasing geometry.

typedef float f32x4 __attribute__((ext_vector_type(4)));

#define BLOCK 256
#define UNROLL 8
#define CHUNK (BLOCK * UNROLL)   // 2048 float4 = 32 KiB per block-iteration

__global__ __launch_bounds__(BLOCK) void ema1d_copy_kernel(
    const f32x4* __restrict__ in, f32x4* __restrict__ out, long n4) {
    long t = threadIdx.x;
    long chunk_stride = (long)gridDim.x * CHUNK;
    long base = (long)blockIdx.x * CHUNK;

    // Main loop: full chunks. 8 independent loads per wave, 4 KiB apart.
    for (; base + CHUNK <= n4; base += chunk_stride) {
        f32x4 v[UNROLL];
#pragma unroll
        for (int u = 0; u < UNROLL; ++u)
            v[u] = in[base + t + (long)u * BLOCK];
#pragma unroll
        for (int u = 0; u < UNROLL; ++u)
            out[base + t + (long)u * BLOCK] = v[u];
    }
    // Tail (not taken for this shape; kept for safety).
    for (long i = base + t; i < n4; i += BLOCK) {
        out[i] = in[i];
    }
}

extern "C" void kernel_launch(void* const* d_in, const int* in_sizes, int n_in,
                              void* d_out, int out_size, void* d_ws, size_t ws_size,
                              hipStream_t stream) {
    const float* x = (const float*)d_in[0];
    float* out = (float*)d_out;

    long n = (long)out_size;   // 67,108,864 elements, divisible by 4
    long n4 = n / 4;           // 16,777,216 float4

    int grid = 2048;           // 8 blocks/CU x 256 CUs; 4 chunk-iters/block

    ema1d_copy_kernel<<<grid, BLOCK, 0, stream>>>(
        (const f32x4*)x, (f32x4*)out, n4);
}

// Round 5
// 93.714 us; speedup vs baseline: 1.0915x; 1.0915x over previous
//
#include <hip/hip_runtime.h>

// EMA1D straight-through: forward value is exactly x, so this is a pure
// 256 MiB -> 256 MiB streaming copy. HBM-bound.
// R1 (grid-stride, 1 load/iter):          112.1 us = 4.79 TB/s
// R2 (4 loads 8 MiB apart + nt):          126.4 us — pow2 channel aliasing
// R3 (4 loads, contiguous 16 KiB chunks):  98.9 us = 5.43 TB/s
// R4 (8 loads, 32 KiB chunks):            102.3 us — deeper MLP neutral/worse
// R5: one-shot grid — 1 float4 per thread, 65536 blocks, NO loop.
//     Grid-stride loops serialize: iter k+1 loads wait on iter k stores
//     which wait on iter k loads (full HBM-latency bubble per iter).
//     One-shot blocks stream loads continuously via HW dispatch/retire —
//     this is the m13 6.29 TB/s copy idiom.

typedef float f32x4 __attribute__((ext_vector_type(4)));

__global__ __launch_bounds__(256) void ema1d_copy_kernel(
    const f32x4* __restrict__ in, f32x4* __restrict__ out, long n4) {
    long i = (long)blockIdx.x * blockDim.x + threadIdx.x;
    if (i < n4) {
        out[i] = in[i];
    }
}

extern "C" void kernel_launch(void* const* d_in, const int* in_sizes, int n_in,
                              void* d_out, int out_size, void* d_ws, size_t ws_size,
                              hipStream_t stream) {
    const float* x = (const float*)d_in[0];
    float* out = (float*)d_out;

    long n = (long)out_size;   // 67,108,864 elements, divisible by 4
    long n4 = n / 4;           // 16,777,216 float4

    int block = 256;
    int grid = (int)((n4 + block - 1) / block);   // 65536 one-shot blocks

    ema1d_copy_kernel<<<grid, block, 0, stream>>>(
        (const f32x4*)x, (f32x4*)out, n4);
}

// Round 6
// 85.588 us; speedup vs baseline: 1.1951x; 1.0949x over previous
//
#include <hip/hip_runtime.h>

// EMA1D straight-through: forward value is exactly x, so this is a pure
// 256 MiB -> 256 MiB streaming copy. HBM-bound.
// R1 (grid-stride, 1 load/iter):          112.1 us = 4.79 TB/s
// R2 (4 loads 8 MiB apart + nt):          126.4 us — pow2 channel aliasing
// R3 (4 loads, contiguous 16 KiB chunks):  98.9 us = 5.43 TB/s
// R4 (8 loads, 32 KiB chunks):            102.3 us — deeper MLP neutral
// R5 (one-shot, 1 float4/thread):          93.7 us = 5.73 TB/s (91% of m13)
// R6: one-shot + nontemporal load/store — isolate nt on the good geometry.
//     512 MiB combined stream = 2x L3; nt skips write-allocate/cache churn
//     for never-re-read data. If neutral -> roofline, revert to R5.

typedef float f32x4 __attribute__((ext_vector_type(4)));

__global__ __launch_bounds__(256) void ema1d_copy_kernel(
    const f32x4* __restrict__ in, f32x4* __restrict__ out, long n4) {
    long i = (long)blockIdx.x * blockDim.x + threadIdx.x;
    if (i < n4) {
        f32x4 v = __builtin_nontemporal_load(in + i);
        __builtin_nontemporal_store(v, out + i);
    }
}

extern "C" void kernel_launch(void* const* d_in, const int* in_sizes, int n_in,
                              void* d_out, int out_size, void* d_ws, size_t ws_size,
                              hipStream_t stream) {
    const float* x = (const float*)d_in[0];
    float* out = (float*)d_out;

    long n = (long)out_size;   // 67,108,864 elements, divisible by 4
    long n4 = n / 4;           // 16,777,216 float4

    int block = 256;
    int grid = (int)((n4 + block - 1) / block);   // 65536 one-shot blocks

    ema1d_copy_kernel<<<grid, block, 0, stream>>>(
        (const f32x4*)x, (f32x4*)out, n4);
}